// Round 5
// baseline (102.407 us; speedup 1.0000x reference)
//
#include <hip/hip_runtime.h>

// Input: (2, 1, 256, 256, 256) float32. x = inputs[:,0] -> (2,256,256,256).
// dd = (core - x[d+1]) * 256 ; dh = (core - x[h+1]) * 256 ; dw = (core - x[w+1]) * 256
// out = mean(|sqrt(dd^2+dh^2+dw^2) - 1|) over 2*255^3 core elements.
//
// Fused single kernel, 2048 blocks (4-plane d-chunks) = 32 waves/CU for
// latency hiding (input is L3-resident: concurrency-bound, not HBM-bound).
// 4-row register pencil per wave; last-block-done deterministic reduction.

#define DVOL 256
#define PLANE (DVOL * DVOL)
#define CORE 255
#define DCH 4
#define NBLK 2048  // 2 b * 64 dchunks * 16 hgroups

__device__ __forceinline__ float sq(float v) { return v * v; }

__device__ __forceinline__ float row_term(const float4 c, const float4 h1,
                                          const float4 d1, int lane, bool valid) {
    const float nx = __shfl_down(c.x, 1, 64);  // lane+1's first element (all lanes participate)
    if (!valid) return 0.0f;
    float acc;
    float s;
    s = sq(c.x - d1.x) + sq(c.x - h1.x) + sq(c.x - c.y);
    acc = fabsf(fmaf(256.0f, sqrtf(s), -1.0f));
    s = sq(c.y - d1.y) + sq(c.y - h1.y) + sq(c.y - c.z);
    acc += fabsf(fmaf(256.0f, sqrtf(s), -1.0f));
    s = sq(c.z - d1.z) + sq(c.z - h1.z) + sq(c.z - c.w);
    acc += fabsf(fmaf(256.0f, sqrtf(s), -1.0f));
    if (lane != 63) {  // w = lane*4+3 = 255 is not core
        s = sq(c.w - d1.w) + sq(c.w - h1.w) + sq(c.w - nx);
        acc += fabsf(fmaf(256.0f, sqrtf(s), -1.0f));
    }
    return acc;
}

__global__ __launch_bounds__(256) void eik_fused(const float* __restrict__ x,
                                                 float* __restrict__ part,
                                                 unsigned int* __restrict__ counter,
                                                 float* __restrict__ out) {
    const int tid  = threadIdx.x;
    const int lane = tid & 63;
    const int wave = tid >> 6;

    const int blk = blockIdx.x;             // [0, 2048)
    const int b   = blk >> 10;              // batch
    const int dc  = (blk >> 4) & 63;        // d-chunk (4 planes)
    const int hg  = (blk & 15) * 4 + wave;  // h-group [0,64), 4 rows each
    const int h   = hg * 4;                 // first row: 0..252
    const int d0  = dc * DCH;
    const int dend = min(d0 + DCH, CORE);   // dc=63: 3 planes
    const bool row3_valid = (h + 3 < CORE); // hg=63: row 255 not core
    const int ch_off = (h + 4 < DVOL) ? 4 * DVOL : 3 * DVOL;  // clamped, unused when invalid

    const float* base = x + (long long)b * (DVOL * PLANE)
                          + (long long)d0 * PLANE
                          + (long long)h * DVOL
                          + lane * 4;

    float4 r0 = *(const float4*)(base);
    float4 r1 = *(const float4*)(base + DVOL);
    float4 r2 = *(const float4*)(base + 2 * DVOL);
    float4 r3 = *(const float4*)(base + 3 * DVOL);

    float acc = 0.0f;
    for (int d = d0; d < dend; ++d) {
        const float4 cd0 = *(const float4*)(base + PLANE);
        const float4 cd1 = *(const float4*)(base + PLANE + DVOL);
        const float4 cd2 = *(const float4*)(base + PLANE + 2 * DVOL);
        const float4 cd3 = *(const float4*)(base + PLANE + 3 * DVOL);
        const float4 ch  = *(const float4*)(base + ch_off);  // row h+4, plane d (cache hit)

        acc += row_term(r0, r1, cd0, lane, true);
        acc += row_term(r1, r2, cd1, lane, true);
        acc += row_term(r2, r3, cd2, lane, true);
        acc += row_term(r3, ch, cd3, lane, row3_valid);

        r0 = cd0; r1 = cd1; r2 = cd2; r3 = cd3;
        base += PLANE;
    }

    // wave shuffle reduction
    #pragma unroll
    for (int off = 32; off > 0; off >>= 1)
        acc += __shfl_down(acc, off, 64);

    __shared__ float wsum[4];
    __shared__ bool isLast;
    if (lane == 0) wsum[wave] = acc;
    __syncthreads();
    if (tid == 0) {
        part[blk] = wsum[0] + wsum[1] + wsum[2] + wsum[3];
        __threadfence();  // make partial visible device-wide before signaling
        unsigned int old = atomicAdd(counter, 1u);
        isLast = (old == NBLK - 1);
    }
    __syncthreads();
    if (!isLast) return;

    // last block: deterministic fixed-order double reduction of 2048 partials
    __threadfence();
    double s = 0.0;
    #pragma unroll
    for (int k = 0; k < 8; ++k)
        s += (double)part[tid + k * 256];
    __shared__ double sm[256];
    sm[tid] = s;
    __syncthreads();
    #pragma unroll
    for (int off = 128; off > 0; off >>= 1) {
        if (tid < off) sm[tid] += sm[tid + off];
        __syncthreads();
    }
    if (tid == 0) {
        const double N = 2.0 * CORE * CORE * CORE;  // 33,162,750
        out[0] = (float)(sm[0] / N);
    }
}

extern "C" void kernel_launch(void* const* d_in, const int* in_sizes, int n_in,
                              void* d_out, int out_size, void* d_ws, size_t ws_size,
                              hipStream_t stream) {
    const float* x = (const float*)d_in[0];
    float* out = (float*)d_out;
    float* part = (float*)d_ws;                                          // 2048 floats
    unsigned int* counter = (unsigned int*)((char*)d_ws + 2048 * sizeof(float));

    hipMemsetAsync(counter, 0, sizeof(unsigned int), stream);
    eik_fused<<<NBLK, 256, 0, stream>>>(x, part, counter, out);
}

// Round 6
// 65.332 us; speedup vs baseline: 1.5675x; 1.5675x over previous
//
#include <hip/hip_runtime.h>

// Input: (2, 1, 256, 256, 256) float32. x = inputs[:,0] -> (2,256,256,256).
// dd = (core - x[d+1]) * 256 ; dh = (core - x[h+1]) * 256 ; dw = (core - x[w+1]) * 256
// out = mean(|sqrt(dd^2+dh^2+dw^2) - 1|) over 2*255^3 core elements.
//
// Geometry (proven round 3): 1024 blocks, 8-plane d-chunks, 4-row register
// pencil per wave (16 waves/CU). Round-5 lesson: 2048 blocks (32 waves/CU)
// collapses DRAM/L3 page locality (40K concurrent streams) -> 3x slower;
// 512 blocks (8 waves/CU) is latency-exposed. 1024 is the sweet spot.
// Fused last-block-done final reduction (deterministic fixed-order tree).

#define DVOL 256
#define PLANE (DVOL * DVOL)
#define CORE 255
#define DCH 8
#define NBLK 1024  // 2 b * 32 dchunks * 16 hgroups

__device__ __forceinline__ float sq(float v) { return v * v; }

__device__ __forceinline__ float row_term(const float4 c, const float4 h1,
                                          const float4 d1, int lane, bool valid) {
    const float nx = __shfl_down(c.x, 1, 64);  // lane+1's first element (all lanes participate)
    if (!valid) return 0.0f;
    float acc;
    float s;
    s = sq(c.x - d1.x) + sq(c.x - h1.x) + sq(c.x - c.y);
    acc = fabsf(fmaf(256.0f, sqrtf(s), -1.0f));
    s = sq(c.y - d1.y) + sq(c.y - h1.y) + sq(c.y - c.z);
    acc += fabsf(fmaf(256.0f, sqrtf(s), -1.0f));
    s = sq(c.z - d1.z) + sq(c.z - h1.z) + sq(c.z - c.w);
    acc += fabsf(fmaf(256.0f, sqrtf(s), -1.0f));
    if (lane != 63) {  // w = lane*4+3 = 255 is not core
        s = sq(c.w - d1.w) + sq(c.w - h1.w) + sq(c.w - nx);
        acc += fabsf(fmaf(256.0f, sqrtf(s), -1.0f));
    }
    return acc;
}

__global__ __launch_bounds__(256) void eik_fused(const float* __restrict__ x,
                                                 float* __restrict__ part,
                                                 unsigned int* __restrict__ counter,
                                                 float* __restrict__ out) {
    const int tid  = threadIdx.x;
    const int lane = tid & 63;
    const int wave = tid >> 6;

    const int blk = blockIdx.x;             // [0, 1024)
    const int b   = blk >> 9;               // batch
    const int dc  = (blk >> 4) & 31;        // d-chunk (8 planes)
    const int hg  = (blk & 15) * 4 + wave;  // h-group [0,64), 4 rows each
    const int h   = hg * 4;                 // first row: 0..252
    const int d0  = dc * DCH;
    const int dend = min(d0 + DCH, CORE);   // dc=31: 7 planes
    const bool row3_valid = (h + 3 < CORE); // hg=63: row 255 not core
    const int ch_off = (h + 4 < DVOL) ? 4 * DVOL : 3 * DVOL;  // clamped, unused when invalid

    const float* base = x + (long long)b * (DVOL * PLANE)
                          + (long long)d0 * PLANE
                          + (long long)h * DVOL
                          + lane * 4;

    float4 r0 = *(const float4*)(base);
    float4 r1 = *(const float4*)(base + DVOL);
    float4 r2 = *(const float4*)(base + 2 * DVOL);
    float4 r3 = *(const float4*)(base + 3 * DVOL);

    float acc = 0.0f;
    for (int d = d0; d < dend; ++d) {
        const float4 cd0 = *(const float4*)(base + PLANE);
        const float4 cd1 = *(const float4*)(base + PLANE + DVOL);
        const float4 cd2 = *(const float4*)(base + PLANE + 2 * DVOL);
        const float4 cd3 = *(const float4*)(base + PLANE + 3 * DVOL);
        const float4 ch  = *(const float4*)(base + ch_off);  // row h+4, plane d (cache hit)

        acc += row_term(r0, r1, cd0, lane, true);
        acc += row_term(r1, r2, cd1, lane, true);
        acc += row_term(r2, r3, cd2, lane, true);
        acc += row_term(r3, ch, cd3, lane, row3_valid);

        r0 = cd0; r1 = cd1; r2 = cd2; r3 = cd3;
        base += PLANE;
    }

    // wave shuffle reduction
    #pragma unroll
    for (int off = 32; off > 0; off >>= 1)
        acc += __shfl_down(acc, off, 64);

    __shared__ float wsum[4];
    __shared__ bool isLast;
    if (lane == 0) wsum[wave] = acc;
    __syncthreads();
    if (tid == 0) {
        part[blk] = wsum[0] + wsum[1] + wsum[2] + wsum[3];
        __threadfence();  // make partial visible device-wide before signaling
        unsigned int old = atomicAdd(counter, 1u);
        isLast = (old == NBLK - 1);
    }
    __syncthreads();
    if (!isLast) return;

    // last block: deterministic fixed-order double reduction of 1024 partials
    __threadfence();
    double s = (double)part[tid] + (double)part[tid + 256]
             + (double)part[tid + 512] + (double)part[tid + 768];
    __shared__ double sm[256];
    sm[tid] = s;
    __syncthreads();
    #pragma unroll
    for (int off = 128; off > 0; off >>= 1) {
        if (tid < off) sm[tid] += sm[tid + off];
        __syncthreads();
    }
    if (tid == 0) {
        const double N = 2.0 * CORE * CORE * CORE;  // 33,162,750
        out[0] = (float)(sm[0] / N);
    }
}

extern "C" void kernel_launch(void* const* d_in, const int* in_sizes, int n_in,
                              void* d_out, int out_size, void* d_ws, size_t ws_size,
                              hipStream_t stream) {
    const float* x = (const float*)d_in[0];
    float* out = (float*)d_out;
    float* part = (float*)d_ws;                                          // 1024 floats
    unsigned int* counter = (unsigned int*)((char*)d_ws + 1024 * sizeof(float));

    hipMemsetAsync(counter, 0, sizeof(unsigned int), stream);
    eik_fused<<<NBLK, 256, 0, stream>>>(x, part, counter, out);
}

// Round 7
// 32.004 us; speedup vs baseline: 3.1998x; 2.0414x over previous
//
#include <hip/hip_runtime.h>

// Input: (2, 1, 256, 256, 256) float32. x = inputs[:,0] -> (2,256,256,256).
// dd = (core - x[d+1]) * 256 ; dh = (core - x[h+1]) * 256 ; dw = (core - x[w+1]) * 256
// out = mean(|sqrt(dd^2+dh^2+dw^2) - 1|) over 2*255^3 core elements.
//
// Round-6 lesson: last-block-done fusion costs ~35ns * NBLK of serialized
// fence+atomic tail (+32us at NBLK=1024) -- far more than the ~5us saved on
// the second launch. Two-kernel structure is strictly better here.
//
// Geometry (proven round 3, 33.2us): 1024 blocks, 8-plane d-chunks, 4-row
// register pencil per wave (16 waves/CU). New: XCD-chunked blockIdx swizzle
// so the 16 blocks sharing each (b,dc) plane-set (and consecutive dc chunks
// sharing boundary planes) land on the same XCD's L2 instead of being
// round-robined across all 8.

#define DVOL 256
#define PLANE (DVOL * DVOL)
#define CORE 255
#define DCH 8
#define NBLK 1024  // 2 b * 32 dchunks * 16 hgroups; 1024 % 8 == 0 -> bijective swizzle

__device__ __forceinline__ float sq(float v) { return v * v; }

__device__ __forceinline__ float row_term(const float4 c, const float4 h1,
                                          const float4 d1, int lane, bool valid) {
    const float nx = __shfl_down(c.x, 1, 64);  // lane+1's first element (all lanes participate)
    if (!valid) return 0.0f;
    float acc;
    float s;
    s = sq(c.x - d1.x) + sq(c.x - h1.x) + sq(c.x - c.y);
    acc = fabsf(fmaf(256.0f, sqrtf(s), -1.0f));
    s = sq(c.y - d1.y) + sq(c.y - h1.y) + sq(c.y - c.z);
    acc += fabsf(fmaf(256.0f, sqrtf(s), -1.0f));
    s = sq(c.z - d1.z) + sq(c.z - h1.z) + sq(c.z - c.w);
    acc += fabsf(fmaf(256.0f, sqrtf(s), -1.0f));
    if (lane != 63) {  // w = lane*4+3 = 255 is not core
        s = sq(c.w - d1.w) + sq(c.w - h1.w) + sq(c.w - nx);
        acc += fabsf(fmaf(256.0f, sqrtf(s), -1.0f));
    }
    return acc;
}

__global__ __launch_bounds__(256) void eik_partial(const float* __restrict__ x,
                                                   float* __restrict__ part) {
    const int tid  = threadIdx.x;
    const int lane = tid & 63;
    const int wave = tid >> 6;

    // XCD-chunked swizzle: hardware round-robins physical blocks across the
    // 8 XCDs (xcd = phys % 8). Map so logical ids [k*128, (k+1)*128) all land
    // on XCD k: logical = (phys & 7) * 128 + (phys >> 3). Bijective for 1024.
    const int blk = ((blockIdx.x & 7) << 7) + (blockIdx.x >> 3);

    const int b   = blk >> 9;               // batch
    const int dc  = (blk >> 4) & 31;        // d-chunk (8 planes)
    const int hg  = (blk & 15) * 4 + wave;  // h-group [0,64), 4 rows each
    const int h   = hg * 4;                 // first row: 0..252
    const int d0  = dc * DCH;
    const int dend = min(d0 + DCH, CORE);   // dc=31: 7 planes
    const bool row3_valid = (h + 3 < CORE); // hg=63: row 255 not core
    const int ch_off = (h + 4 < DVOL) ? 4 * DVOL : 3 * DVOL;  // clamped, unused when invalid

    const float* base = x + (long long)b * (DVOL * PLANE)
                          + (long long)d0 * PLANE
                          + (long long)h * DVOL
                          + lane * 4;

    float4 r0 = *(const float4*)(base);
    float4 r1 = *(const float4*)(base + DVOL);
    float4 r2 = *(const float4*)(base + 2 * DVOL);
    float4 r3 = *(const float4*)(base + 3 * DVOL);

    float acc = 0.0f;
    for (int d = d0; d < dend; ++d) {
        const float4 cd0 = *(const float4*)(base + PLANE);
        const float4 cd1 = *(const float4*)(base + PLANE + DVOL);
        const float4 cd2 = *(const float4*)(base + PLANE + 2 * DVOL);
        const float4 cd3 = *(const float4*)(base + PLANE + 3 * DVOL);
        const float4 ch  = *(const float4*)(base + ch_off);  // row h+4, plane d (cache hit)

        acc += row_term(r0, r1, cd0, lane, true);
        acc += row_term(r1, r2, cd1, lane, true);
        acc += row_term(r2, r3, cd2, lane, true);
        acc += row_term(r3, ch, cd3, lane, row3_valid);

        r0 = cd0; r1 = cd1; r2 = cd2; r3 = cd3;
        base += PLANE;
    }

    // wave shuffle reduction
    #pragma unroll
    for (int off = 32; off > 0; off >>= 1)
        acc += __shfl_down(acc, off, 64);

    __shared__ float wsum[4];
    if (lane == 0) wsum[wave] = acc;
    __syncthreads();
    if (tid == 0)
        part[blk] = wsum[0] + wsum[1] + wsum[2] + wsum[3];
}

__global__ void eik_final(const float* __restrict__ part, float* __restrict__ out) {
    const int tid = threadIdx.x;
    double s = (double)part[tid] + (double)part[tid + 256]
             + (double)part[tid + 512] + (double)part[tid + 768];

    __shared__ double sm[256];
    sm[tid] = s;
    __syncthreads();
    #pragma unroll
    for (int off = 128; off > 0; off >>= 1) {
        if (tid < off) sm[tid] += sm[tid + off];
        __syncthreads();
    }
    if (tid == 0) {
        const double N = 2.0 * CORE * CORE * CORE;  // 33,162,750
        out[0] = (float)(sm[0] / N);
    }
}

extern "C" void kernel_launch(void* const* d_in, const int* in_sizes, int n_in,
                              void* d_out, int out_size, void* d_ws, size_t ws_size,
                              hipStream_t stream) {
    const float* x = (const float*)d_in[0];
    float* out = (float*)d_out;
    float* part = (float*)d_ws;  // 1024 floats = 4 KB

    eik_partial<<<NBLK, 256, 0, stream>>>(x, part);
    eik_final<<<1, 256, 0, stream>>>(part, out);
}